// Round 4
// baseline (307.993 us; speedup 1.0000x reference)
//
#include <hip/hip_runtime.h>

#define PTS    4096
#define TPB    256
#define PPB    64      // points per block (merge lane count)
#define QTR    1024    // candidates scanned per thread (4-way split)
#define NSUB   32      // substream minima per thread (fits registers!)
#define CAP    36      // collect slots per thread
#define NCLOUD 16
#define NTOT   (NCLOUD * PTS)
#define UMAX   0xFFFFFFFFu

typedef __attribute__((ext_vector_type(2))) float f32x2;

// insert key into unsorted top-N (s holds the N smallest seen, cmax = max of s)
template<int N>
__device__ __forceinline__ void insN(unsigned key, unsigned (&s)[N], unsigned &cmax) {
  if (key < cmax) {
    bool done = false;
#pragma unroll
    for (int i = 0; i < N; ++i) {
      bool c = (!done) && (s[i] == cmax);
      s[i] = c ? key : s[i];
      done = done || c;
    }
    cmax = s[0];
#pragma unroll
    for (int i = 1; i < N; ++i) cmax = (s[i] > cmax) ? s[i] : cmax;
  }
}

// AoS xyz -> SoA xs/ys/zs in workspace
__global__ void soa_pack(const float* __restrict__ x, float* __restrict__ ws) {
  const int g = blockIdx.x * TPB + threadIdx.x;
  ws[g]            = x[3 * g + 0];
  ws[NTOT + g]     = x[3 * g + 1];
  ws[2 * NTOT + g] = x[3 * g + 2];
}

__global__ __launch_bounds__(TPB, 4) void knn_cov_soa(const float* __restrict__ ws,
                                                      float* __restrict__ out) {
  __shared__ unsigned scol[CAP * TPB];  // 36 KB: per-thread collect columns
  __shared__ unsigned scnt[TPB];        // 1 KB  -> 4 blocks/CU

  const int tid   = threadIdx.x;
  const int lane  = tid & 63;
  const int h     = __builtin_amdgcn_readfirstlane(tid >> 6);  // wave = quarter
  const int cloud = blockIdx.x >> 6;
  const int chunk = blockIdx.x & 63;
  const int p     = chunk * PPB + lane;

  const float* __restrict__ Xs = ws + (size_t)cloud * PTS;
  const float* __restrict__ Ys = Xs + NTOT;
  const float* __restrict__ Zs = Xs + 2 * NTOT;

  const float px = Xs[p], py = Ys[p], pz = Zs[p];
  f32x2 vx; vx.x = px; vx.y = px;
  f32x2 vy; vy.x = py; vy.y = py;
  f32x2 vz; vz.x = pz; vz.y = pz;

  const int c0 = h * QTR;
  const float* __restrict__ qx = Xs + c0;
  const float* __restrict__ qy = Ys + c0;
  const float* __restrict__ qz = Zs + c0;

  // ---- pass 1: 32 substream minima as 16 packed pairs (in registers)
  f32x2 m2[16];
#pragma unroll
  for (int j = 0; j < 16; ++j) { m2[j].x = 3.4e38f; m2[j].y = 3.4e38f; }
  for (int t0 = 0; t0 < QTR; t0 += NSUB) {
#pragma unroll
    for (int j = 0; j < 16; ++j) {
      const int i2 = (t0 >> 1) + j;
      const f32x2 ax = *(const f32x2*)(qx + 2 * i2);
      const f32x2 ay = *(const f32x2*)(qy + 2 * i2);
      const f32x2 az = *(const f32x2*)(qz + 2 * i2);
      const f32x2 dx = ax - vx, dy = ay - vy, dz = az - vz;
      const f32x2 d  = dx * dx + dy * dy + dz * dz;
      m2[j].x = fminf(m2[j].x, d.x);
      m2[j].y = fminf(m2[j].y, d.y);
    }
  }

  // ---- threshold = 17th smallest of 32 minima (rank 17 absorbs self d=0)
  float mm[32];
#pragma unroll
  for (int j = 0; j < 16; ++j) { mm[2 * j] = m2[j].x; mm[2 * j + 1] = m2[j].y; }
  unsigned s17[17], cm;
#pragma unroll
  for (int j = 0; j < 17; ++j) s17[j] = __float_as_uint(mm[j]);
  cm = s17[0];
#pragma unroll
  for (int j = 1; j < 17; ++j) cm = (s17[j] > cm) ? s17[j] : cm;
#pragma unroll
  for (int j = 17; j < NSUB; ++j) insN<17>(__float_as_uint(mm[j]), s17, cm);
  const float Tval = __uint_as_float(cm);

  // ---- pass 2: collect all d <= T into LDS columns (packed math, keyed)
  unsigned cnt = 0;
  for (int t0 = 0; t0 < QTR; t0 += 16) {
#pragma unroll
    for (int j = 0; j < 8; ++j) {
      const int i2 = (t0 >> 1) + j;
      const f32x2 ax = *(const f32x2*)(qx + 2 * i2);
      const f32x2 ay = *(const f32x2*)(qy + 2 * i2);
      const f32x2 az = *(const f32x2*)(qz + 2 * i2);
      const f32x2 dx = ax - vx, dy = ay - vy, dz = az - vz;
      const f32x2 d  = dx * dx + dy * dy + dz * dz;
      if (d.x <= Tval) {
        const unsigned slot = (cnt < (unsigned)CAP) ? cnt : (unsigned)(CAP - 1);
        scol[slot * TPB + tid] =
            (__float_as_uint(d.x) & 0xFFFFF000u) | (unsigned)(c0 + 2 * i2);
        cnt++;
      }
      if (d.y <= Tval) {
        const unsigned slot = (cnt < (unsigned)CAP) ? cnt : (unsigned)(CAP - 1);
        scol[slot * TPB + tid] =
            (__float_as_uint(d.y) & 0xFFFFF000u) | (unsigned)(c0 + 2 * i2 + 1);
        cnt++;
      }
    }
  }

  // ---- overflow fallback (~5 sigma): exact top-17 rescan of this quarter
  if (cnt > (unsigned)CAP) {
    unsigned sf[17], cmf = UMAX;
#pragma unroll
    for (int j = 0; j < 17; ++j) sf[j] = UMAX;
#pragma unroll 4
    for (int ci = 0; ci < QTR; ++ci) {
      const float dx = qx[ci] - px, dy = qy[ci] - py, dz = qz[ci] - pz;
      const float d  = fmaf(dz, dz, fmaf(dy, dy, dx * dx));
      insN<17>((__float_as_uint(d) & 0xFFFFF000u) | (unsigned)(c0 + ci), sf, cmf);
    }
#pragma unroll
    for (int j = 0; j < 17; ++j) scol[j * TPB + tid] = sf[j];
    cnt = 17;
  }
  scnt[tid] = cnt;
  __syncthreads();

  // ---- merge the 4 quarters' candidate sets (wave 0), cov, store
  if (tid < PPB) {
    unsigned s16[16], cm16 = UMAX;
#pragma unroll
    for (int j = 0; j < 16; ++j) s16[j] = UMAX;
    const unsigned selfk = (unsigned)p;  // self: d==+0 exactly -> key = index
#pragma unroll
    for (int k = 0; k < 4; ++k) {
      const int col = k * PPB + tid;
      const unsigned n = scnt[col];
      unsigned w = n;
#pragma unroll
      for (int off = 32; off >= 1; off >>= 1) {
        unsigned o = (unsigned)__shfl_xor((int)w, off, 64);
        w = (o > w) ? o : w;
      }
      for (unsigned j = 0; j < w; ++j) {
        unsigned kb = (j < n) ? scol[j * TPB + col] : UMAX;
        kb = (kb == selfk) ? UMAX : kb;
        insN<16>(kb, s16, cm16);
      }
    }

    float Sx = 0, Sy = 0, Sz = 0;
    float Sxx = 0, Sxy = 0, Sxz = 0, Syy = 0, Syz = 0, Szz = 0;
#pragma unroll
    for (int j = 0; j < 16; ++j) {
      const int idx = (int)(s16[j] & 0xFFFu);
      const float nx = Xs[idx], ny = Ys[idx], nz = Zs[idx];
      Sx += nx; Sy += ny; Sz += nz;
      Sxx = fmaf(nx, nx, Sxx); Sxy = fmaf(nx, ny, Sxy); Sxz = fmaf(nx, nz, Sxz);
      Syy = fmaf(ny, ny, Syy); Syz = fmaf(ny, nz, Syz); Szz = fmaf(nz, nz, Szz);
    }
    const float sc = 0.0625f;
    const float mx = Sx * sc, my = Sy * sc, mz = Sz * sc;
    const float cxx = fmaf(-mx, mx, Sxx * sc);
    const float cxy = fmaf(-mx, my, Sxy * sc);
    const float cxz = fmaf(-mx, mz, Sxz * sc);
    const float cyy = fmaf(-my, my, Syy * sc);
    const float cyz = fmaf(-my, mz, Syz * sc);
    const float czz = fmaf(-mz, mz, Szz * sc);

    const int gid = cloud * PTS + p;
    float4* o4 = (float4*)(out + (size_t)gid * 12);
    o4[0] = make_float4(px, py, pz, cxx);
    o4[1] = make_float4(cxy, cxz, cxy, cyy);
    o4[2] = make_float4(cyz, cxz, cyz, czz);
  }
}

// ---- AoS fallback (only if ws_size too small): round-3 structure, NSUB=32
__global__ __launch_bounds__(TPB, 4) void knn_cov_aos(const float* __restrict__ x,
                                                      float* __restrict__ out) {
  __shared__ unsigned scol[CAP * TPB];
  __shared__ unsigned scnt[TPB];

  const int tid   = threadIdx.x;
  const int lane  = tid & 63;
  const int h     = __builtin_amdgcn_readfirstlane(tid >> 6);
  const int cloud = blockIdx.x >> 6;
  const int chunk = blockIdx.x & 63;
  const int p     = chunk * PPB + lane;

  const float* __restrict__ xc = x + (size_t)cloud * PTS * 3;
  const float px = xc[p * 3 + 0], py = xc[p * 3 + 1], pz = xc[p * 3 + 2];
  const int c0 = h * QTR;
  const float* __restrict__ cc = xc + (size_t)c0 * 3;

  float m[NSUB];
#pragma unroll
  for (int j = 0; j < NSUB; ++j) m[j] = 3.4e38f;
  for (int t0 = 0; t0 < QTR; t0 += NSUB) {
#pragma unroll
    for (int j = 0; j < NSUB; ++j) {
      const int ci = t0 + j;
      const float dx = cc[ci * 3 + 0] - px, dy = cc[ci * 3 + 1] - py,
                  dz = cc[ci * 3 + 2] - pz;
      const float d = fmaf(dz, dz, fmaf(dy, dy, dx * dx));
      m[j] = fminf(m[j], d);
    }
  }
  unsigned s17[17], cm;
#pragma unroll
  for (int j = 0; j < 17; ++j) s17[j] = __float_as_uint(m[j]);
  cm = s17[0];
#pragma unroll
  for (int j = 1; j < 17; ++j) cm = (s17[j] > cm) ? s17[j] : cm;
#pragma unroll
  for (int j = 17; j < NSUB; ++j) insN<17>(__float_as_uint(m[j]), s17, cm);
  const float Tval = __uint_as_float(cm);

  unsigned cnt = 0;
  for (int t0 = 0; t0 < QTR; t0 += 8) {
#pragma unroll
    for (int j = 0; j < 8; ++j) {
      const int ci = t0 + j;
      const float dx = cc[ci * 3 + 0] - px, dy = cc[ci * 3 + 1] - py,
                  dz = cc[ci * 3 + 2] - pz;
      const float d = fmaf(dz, dz, fmaf(dy, dy, dx * dx));
      if (d <= Tval) {
        const unsigned slot = (cnt < (unsigned)CAP) ? cnt : (unsigned)(CAP - 1);
        scol[slot * TPB + tid] =
            (__float_as_uint(d) & 0xFFFFF000u) | (unsigned)(c0 + ci);
        cnt++;
      }
    }
  }
  if (cnt > (unsigned)CAP) {
    unsigned sf[17], cmf = UMAX;
#pragma unroll
    for (int j = 0; j < 17; ++j) sf[j] = UMAX;
#pragma unroll 4
    for (int ci = 0; ci < QTR; ++ci) {
      const float dx = cc[ci * 3 + 0] - px, dy = cc[ci * 3 + 1] - py,
                  dz = cc[ci * 3 + 2] - pz;
      const float d = fmaf(dz, dz, fmaf(dy, dy, dx * dx));
      insN<17>((__float_as_uint(d) & 0xFFFFF000u) | (unsigned)(c0 + ci), sf, cmf);
    }
#pragma unroll
    for (int j = 0; j < 17; ++j) scol[j * TPB + tid] = sf[j];
    cnt = 17;
  }
  scnt[tid] = cnt;
  __syncthreads();

  if (tid < PPB) {
    unsigned s16[16], cm16 = UMAX;
#pragma unroll
    for (int j = 0; j < 16; ++j) s16[j] = UMAX;
    const unsigned selfk = (unsigned)p;
#pragma unroll
    for (int k = 0; k < 4; ++k) {
      const int col = k * PPB + tid;
      const unsigned n = scnt[col];
      unsigned w = n;
#pragma unroll
      for (int off = 32; off >= 1; off >>= 1) {
        unsigned o = (unsigned)__shfl_xor((int)w, off, 64);
        w = (o > w) ? o : w;
      }
      for (unsigned j = 0; j < w; ++j) {
        unsigned kb = (j < n) ? scol[j * TPB + col] : UMAX;
        kb = (kb == selfk) ? UMAX : kb;
        insN<16>(kb, s16, cm16);
      }
    }
    float Sx = 0, Sy = 0, Sz = 0;
    float Sxx = 0, Sxy = 0, Sxz = 0, Syy = 0, Syz = 0, Szz = 0;
#pragma unroll
    for (int j = 0; j < 16; ++j) {
      const int idx = (int)(s16[j] & 0xFFFu);
      const float nx = xc[idx * 3 + 0], ny = xc[idx * 3 + 1], nz = xc[idx * 3 + 2];
      Sx += nx; Sy += ny; Sz += nz;
      Sxx = fmaf(nx, nx, Sxx); Sxy = fmaf(nx, ny, Sxy); Sxz = fmaf(nx, nz, Sxz);
      Syy = fmaf(ny, ny, Syy); Syz = fmaf(ny, nz, Syz); Szz = fmaf(nz, nz, Szz);
    }
    const float sc = 0.0625f;
    const float mx = Sx * sc, my = Sy * sc, mz = Sz * sc;
    const float cxx = fmaf(-mx, mx, Sxx * sc);
    const float cxy = fmaf(-mx, my, Sxy * sc);
    const float cxz = fmaf(-mx, mz, Sxz * sc);
    const float cyy = fmaf(-my, my, Syy * sc);
    const float cyz = fmaf(-my, mz, Syz * sc);
    const float czz = fmaf(-mz, mz, Szz * sc);

    const int gid = cloud * PTS + p;
    float4* o4 = (float4*)(out + (size_t)gid * 12);
    o4[0] = make_float4(px, py, pz, cxx);
    o4[1] = make_float4(cxy, cxz, cxy, cyy);
    o4[2] = make_float4(cyz, cxz, cyz, czz);
  }
}

extern "C" void kernel_launch(void* const* d_in, const int* in_sizes, int n_in,
                              void* d_out, int out_size, void* d_ws, size_t ws_size,
                              hipStream_t stream) {
  const float* x = (const float*)d_in[0];
  float* out = (float*)d_out;
  dim3 grid(NCLOUD * (PTS / PPB));  // 1024 blocks = 4/CU
  if (ws_size >= (size_t)3 * NTOT * sizeof(float)) {
    float* ws = (float*)d_ws;
    soa_pack<<<NTOT / TPB, TPB, 0, stream>>>(x, ws);
    knn_cov_soa<<<grid, TPB, 0, stream>>>(ws, out);
  } else {
    knn_cov_aos<<<grid, TPB, 0, stream>>>(x, out);
  }
}